// Round 1
// baseline (180.538 us; speedup 1.0000x reference)
//
#include <hip/hip_runtime.h>
#include <math.h>

#define NBINS   15
#define CDIM    1000
#define QDIM    250                 // CDIM / 4
#define HIST_ELEMS (NBINS * CDIM)
#define THREADS 512
#define NWAVES  (THREADS / 64)      // 8 waves per block
#define PAD     -1000.0f            // exp(PAD) == 0 exactly -> conf == 0 -> add == 0
#define RARE_LIM (1.0f)             // conf*15 > 1  <=> beyond bin 0

__device__ __forceinline__ float waveSum(float v) {
#pragma unroll
    for (int o = 32; o > 0; o >>= 1) v += __shfl_xor(v, o, 64);
    return v;
}

__device__ __forceinline__ void loadRow(float4 (&v)[4], int& label,
                                        const float* __restrict__ logits,
                                        const int* __restrict__ labels,
                                        int r, int lane) {
    const float4* row = (const float4*)(logits + (size_t)r * CDIM);
#pragma unroll
    for (int j = 0; j < 3; ++j) v[j] = row[lane + 64 * j];     // q < 192 < QDIM always
    v[3] = make_float4(PAD, PAD, PAD, PAD);
    if (lane < QDIM - 192) v[3] = row[lane + 192];             // lanes 0..57
    label = labels[r];
}

// Hot path: exp pass (mul+exp+add+max per elem), wave sum, then ONE fmac per
// element. Label indicator and rare bins (>1/15, ~85 events total) are handled
// per-row behind wave-uniform branches — zero per-element exec-mask churn.
__device__ __forceinline__ void computeRow(float4 (&v)[4], int label, int lane,
                                           float (&regAcc)[4][4],
                                           float* __restrict__ D) {
    float s = 0.0f, m = 0.0f;
#pragma unroll
    for (int j = 0; j < 4; ++j) {
        v[j].x = __expf(v[j].x);
        v[j].y = __expf(v[j].y);
        v[j].z = __expf(v[j].z);
        v[j].w = __expf(v[j].w);
        s += (v[j].x + v[j].y) + (v[j].z + v[j].w);
        m = fmaxf(m, fmaxf(fmaxf(v[j].x, v[j].y), fmaxf(v[j].z, v[j].w)));
    }
    s = waveSum(s);
    const float inv = 1.0f / s;

    // Exact: *inv and *15 are monotone, so max-of-predicate == predicate-of-max.
    const bool rare = __any((m * inv) * 15.0f > RARE_LIM);

    if (!rare) {
        // Common path: every element lands in bin 0. One v_fmac each.
#pragma unroll
        for (int j = 0; j < 4; ++j) {
            regAcc[j][0] = fmaf(v[j].x, inv, regAcc[j][0]);
            regAcc[j][1] = fmaf(v[j].y, inv, regAcc[j][1]);
            regAcc[j][2] = fmaf(v[j].z, inv, regAcc[j][2]);
            regAcc[j][3] = fmaf(v[j].w, inv, regAcc[j][3]);
        }
    } else {
        // Rare row (~85 in 65536): full per-element bin logic, same math as before.
#pragma unroll
        for (int j = 0; j < 4; ++j) {
            const int q = lane + 64 * j;
            const float cf[4] = {v[j].x, v[j].y, v[j].z, v[j].w};
#pragma unroll
            for (int k = 0; k < 4; ++k) {
                float conf = cf[k] * inv;
                float t    = conf * 15.0f;
                if (t > RARE_LIM) {
                    int b = min((int)ceilf(t) - 1, NBINS - 1);
                    unsafeAtomicAdd(&D[b * CDIM + k * QDIM + q], conf);
                } else {
                    regAcc[j][k] += conf;
                }
            }
        }
    }

    // Label correction: subtract 1.0 in the bin of conf_label at the label's
    // slot. label is wave-uniform -> scalar indices, scalar branch tree.
    const int sl    = __builtin_amdgcn_readfirstlane(label);
    const int lq    = sl >> 2;        // quad index 0..249
    const int lk    = sl & 3;         // component
    const int lj    = lq >> 6;        // buffer index 0..3
    const int llane = lq & 63;        // owning lane

    float cfl;
    if      (lj == 0) cfl = (lk == 0) ? v[0].x : (lk == 1) ? v[0].y : (lk == 2) ? v[0].z : v[0].w;
    else if (lj == 1) cfl = (lk == 0) ? v[1].x : (lk == 1) ? v[1].y : (lk == 2) ? v[1].z : v[1].w;
    else if (lj == 2) cfl = (lk == 0) ? v[2].x : (lk == 1) ? v[2].y : (lk == 2) ? v[2].z : v[2].w;
    else              cfl = (lk == 0) ? v[3].x : (lk == 1) ? v[3].y : (lk == 2) ? v[3].z : v[3].w;

    const float confl = cfl * inv;
    const bool  own   = (lane == llane);

    if (own && confl * 15.0f > RARE_LIM) {
        // label element sits beyond bin 0 (vanishingly rare): native atomic -1
        int b = min((int)ceilf(confl * 15.0f) - 1, NBINS - 1);
        unsafeAtomicAdd(&D[b * CDIM + lk * QDIM + lq], -1.0f);
    } else {
        const float dec = own ? 1.0f : 0.0f;   // non-owners subtract exact 0.0
#define LBL_CASE(J)                                                         \
        if (lj == J) {                                                      \
            if      (lk == 0) regAcc[J][0] -= dec;                          \
            else if (lk == 1) regAcc[J][1] -= dec;                          \
            else if (lk == 2) regAcc[J][2] -= dec;                          \
            else              regAcc[J][3] -= dec;                          \
        }
        LBL_CASE(0) else LBL_CASE(1) else LBL_CASE(2) else LBL_CASE(3)
#undef LBL_CASE
    }
}

// Global D layout: index = b*CDIM + k*QDIM + q, class c = 4*q + k (bijective;
// the final sum of |D| is layout-invariant).
__global__ __launch_bounds__(THREADS, 4) void ece_hist_kernel(
        const float* __restrict__ logits,
        const int*   __restrict__ labels,
        float*       __restrict__ D,
        int N, int rowsPerBlock)
{
    __shared__ float sB[CDIM];           // 4 KB: block-level bin-0 reduce

    const int tid  = threadIdx.x;
    const int lane = tid & 63;
    const int w    = tid >> 6;           // wave id 0..7

    for (int i = tid; i < CDIM; i += THREADS) sB[i] = 0.0f;
    __syncthreads();

    const int r0 = blockIdx.x * rowsPerBlock;
    const int r1 = min(r0 + rowsPerBlock, N);

    float regAcc[4][4];
#pragma unroll
    for (int j = 0; j < 4; ++j)
#pragma unroll
        for (int k = 0; k < 4; ++k) regAcc[j][k] = 0.0f;

    // --- 4-buffer software pipeline: while computing row i, loads for rows
    //     i+1, i+2, i+3 are in flight (~12 KB/wave outstanding). All buffer
    //     indices static; all guards wave-uniform.
    float4 vA[4], vB[4], vC[4], vD2[4];
    int    lA = 0, lB = 0, lC = 0, lD = 0;

    int rA = r0 + w;                     // this wave's rows: rA, rA+8, rA+16, ...
    int rB = rA + NWAVES;
    int rC = rB + NWAVES;
    int rD = rC + NWAVES;

    if (rA < r1) loadRow(vA,  lA, logits, labels, rA, lane);
    if (rB < r1) loadRow(vB,  lB, logits, labels, rB, lane);
    if (rC < r1) loadRow(vC,  lC, logits, labels, rC, lane);
    if (rD < r1) loadRow(vD2, lD, logits, labels, rD, lane);

    while (rA < r1) {
        computeRow(vA, lA, lane, regAcc, D);
        rA = rD + NWAVES;
        if (rA < r1) loadRow(vA, lA, logits, labels, rA, lane);

        if (rB >= r1) break;
        computeRow(vB, lB, lane, regAcc, D);
        rB = rA + NWAVES;
        if (rB < r1) loadRow(vB, lB, logits, labels, rB, lane);

        if (rC >= r1) break;
        computeRow(vC, lC, lane, regAcc, D);
        rC = rB + NWAVES;
        if (rC < r1) loadRow(vC, lC, logits, labels, rC, lane);

        if (rD >= r1) break;
        computeRow(vD2, lD, lane, regAcc, D);
        rD = rC + NWAVES;
        if (rD < r1) loadRow(vD2, lD, logits, labels, rD, lane);
    }

    // Block-level reduce of bin-0 registers (once per block, native ds_add).
#pragma unroll
    for (int j = 0; j < 4; ++j) {
        int q = lane + 64 * j;
        if (q < QDIM) {
#pragma unroll
            for (int k = 0; k < 4; ++k)
                unsafeAtomicAdd(&sB[k * QDIM + q], regAcc[j][k]);
        }
    }

    __syncthreads();
    // Flush bin-0 partials to global (1000 atomics per block).
    for (int i = tid; i < CDIM; i += THREADS) {
        float val = sB[i];
        if (val != 0.0f) unsafeAtomicAdd(&D[i], val);
    }
}

__global__ __launch_bounds__(1024) void ece_final_kernel(
        const float* __restrict__ D, float* __restrict__ out, float scale)
{
    float s = 0.0f;
    const float4* D4 = (const float4*)D;          // HIST_ELEMS % 4 == 0
    for (int i = threadIdx.x; i < HIST_ELEMS / 4; i += 1024) {
        float4 t = D4[i];
        s += (fabsf(t.x) + fabsf(t.y)) + (fabsf(t.z) + fabsf(t.w));
    }
    s = waveSum(s);
    __shared__ float sr[16];
    const int lane = threadIdx.x & 63;
    const int wid  = threadIdx.x >> 6;
    if (lane == 0) sr[wid] = s;
    __syncthreads();
    if (threadIdx.x == 0) {
        float t = 0.0f;
#pragma unroll
        for (int ww = 0; ww < 16; ++ww) t += sr[ww];
        out[0] = t * scale;
    }
}

extern "C" void kernel_launch(void* const* d_in, const int* in_sizes, int n_in,
                              void* d_out, int out_size, void* d_ws, size_t ws_size,
                              hipStream_t stream)
{
    const float* logits = (const float*)d_in[0];
    const int*   labels = (const int*)d_in[1];

    const int N = in_sizes[1];                        // 65536 rows

    float* D = (float*)d_ws;
    hipMemsetAsync(D, 0, HIST_ELEMS * sizeof(float), stream);

    const int grid = 512;                             // 2 blocks/CU, 16 rows/wave
    const int rowsPerBlock = (N + grid - 1) / grid;   // 128

    ece_hist_kernel<<<grid, THREADS, 0, stream>>>(logits, labels, D, N, rowsPerBlock);

    const float scale = 1.0f / ((float)N * (float)CDIM);
    ece_final_kernel<<<1, 1024, 0, stream>>>(D, (float*)d_out, scale);
}